// Round 2
// baseline (359.665 us; speedup 1.0000x reference)
//
#include <hip/hip_runtime.h>
#include <stdint.h>

#define BB 4
#define CC 512
#define NN 4096
#define DQd 64

typedef unsigned short u16;
typedef unsigned int u32;
typedef __bf16 bf16x8 __attribute__((ext_vector_type(8)));
typedef float f32x4 __attribute__((ext_vector_type(4)));

__device__ __forceinline__ u16 f2bf(float f) {
  union { float f; u32 u; } v; v.f = f;
  u32 r = v.u + 0x7FFFu + ((v.u >> 16) & 1u);
  return (u16)(r >> 16);
}

__device__ __forceinline__ bf16x8 ld_bf8(const u16* p) {
  return *reinterpret_cast<const bf16x8*>(p);
}

__device__ __forceinline__ f32x4 mfma16(bf16x8 a, bf16x8 b, f32x4 c) {
  return __builtin_amdgcn_mfma_f32_16x16x32_bf16(a, b, c, 0, 0, 0);
}

// ---------------- Kernel 1: x [B][C][N] f32 -> Xt [B][N][C] bf16 ----------------
__global__ __launch_bounds__(256) void k_transpose(const float* __restrict__ x,
                                                   u16* __restrict__ xt) {
  __shared__ float tile[32][33];
  const int b = blockIdx.z;
  const int n0 = blockIdx.x * 32;
  const int c0 = blockIdx.y * 32;
  const int tj = threadIdx.x & 31;
  const int ti = threadIdx.x >> 5;
  const float* xb = x + (size_t)b * CC * NN;
  #pragma unroll
  for (int i = ti; i < 32; i += 8)
    tile[i][tj] = xb[(size_t)(c0 + i) * NN + (n0 + tj)];
  __syncthreads();
  u16* xtb = xt + (size_t)b * NN * CC;
  #pragma unroll
  for (int i = ti; i < 32; i += 8)
    xtb[(size_t)(n0 + i) * CC + (c0 + tj)] = f2bf(tile[tj][i]);
}

// ------------- Kernel 2: Q,K projection -> Q,K [B][N][64] bf16 -------------
// Block 512 thr (8 waves). BM=64 rows of n, 128 output cols (Q:0..63, K:64..127).
// wave w: rows (w&3)*16, col-half (w>>2).
__global__ __launch_bounds__(512) void k_proj_qk(
    const u16* __restrict__ xt, const float* __restrict__ Wq, const float* __restrict__ bq,
    const float* __restrict__ Wk, const float* __restrict__ bk,
    u16* __restrict__ Qo, u16* __restrict__ Ko) {
  __shared__ __align__(16) u16 wl[128 * 64];
  const int b = blockIdx.y;
  const int n0 = blockIdx.x * 64;
  const int t = threadIdx.x;
  const int w = t >> 6, l = t & 63, g = l >> 4, l15 = l & 15;
  const int rw = w & 3, ch = w >> 2;
  f32x4 acc[4];
  #pragma unroll
  for (int i = 0; i < 4; ++i) acc[i] = f32x4{0.f, 0.f, 0.f, 0.f};
  const u16* xrow = xt + (size_t)(b * NN + n0 + rw * 16 + l15) * CC;

  for (int kt = 0; kt < 8; ++kt) {
    // stage W tile [128 o][64 c] bf16, XOR-swizzled 16B chunks
    #pragma unroll
    for (int i = 0; i < 16; ++i) {
      int e = i * 512 + t;
      int o = e >> 6, cc = e & 63;
      float wv = (o < 64) ? Wq[(size_t)o * CC + kt * 64 + cc]
                          : Wk[(size_t)(o - 64) * CC + kt * 64 + cc];
      wl[o * 64 + ((((cc >> 3) ^ (o & 7)) << 3) | (cc & 7))] = f2bf(wv);
    }
    __syncthreads();
    #pragma unroll
    for (int ks = 0; ks < 2; ++ks) {
      bf16x8 a = ld_bf8(xrow + kt * 64 + ks * 32 + g * 8);
      #pragma unroll
      for (int cf = 0; cf < 4; ++cf) {
        int o = (ch * 4 + cf) * 16 + l15;
        bf16x8 bb = ld_bf8(&wl[o * 64 + (((ks * 4 + g) ^ (o & 7)) << 3)]);
        acc[cf] = mfma16(a, bb, acc[cf]);
      }
    }
    __syncthreads();
  }
  #pragma unroll
  for (int cf = 0; cf < 4; ++cf) {
    int o = (ch * 4 + cf) * 16 + l15;
    float bias = (o < 64) ? bq[o] : bk[o - 64];
    #pragma unroll
    for (int r = 0; r < 4; ++r) {
      int n = n0 + rw * 16 + g * 4 + r;
      u16 val = f2bf(acc[cf][r] + bias);
      if (o < 64) Qo[(size_t)(b * NN + n) * DQd + o] = val;
      else        Ko[(size_t)(b * NN + n) * DQd + (o - 64)] = val;
    }
  }
}

// ------------- Kernel 3: V projection -> Vt [B][512][N] bf16 (transposed) -------------
// D[row=c_out][col=n]; A = Wv (LDS staged), B = Xt rows (global).
// Block 256 thr (4 waves), tile 128 c_out x 128 n, BK=64.
__global__ __launch_bounds__(256) void k_proj_v(
    const u16* __restrict__ xt, const float* __restrict__ Wv, const float* __restrict__ bv,
    u16* __restrict__ Vt) {
  __shared__ __align__(16) u16 wl[128 * 64];
  const int b = blockIdx.z;
  const int co0 = blockIdx.y * 128;
  const int n0 = blockIdx.x * 128;
  const int t = threadIdx.x;
  const int w = t >> 6, l = t & 63, g = l >> 4, l15 = l & 15;
  f32x4 acc[2][8];
  #pragma unroll
  for (int i = 0; i < 2; ++i)
    #pragma unroll
    for (int j = 0; j < 8; ++j) acc[i][j] = f32x4{0.f, 0.f, 0.f, 0.f};

  for (int kt = 0; kt < 8; ++kt) {
    #pragma unroll
    for (int i = 0; i < 32; ++i) {
      int e = i * 256 + t;
      int o = e >> 6, cc = e & 63;
      float wv = Wv[(size_t)(co0 + o) * CC + kt * 64 + cc];
      wl[o * 64 + ((((cc >> 3) ^ (o & 7)) << 3) | (cc & 7))] = f2bf(wv);
    }
    __syncthreads();
    #pragma unroll
    for (int ks = 0; ks < 2; ++ks) {
      int o0 = w * 32 + l15, o1 = w * 32 + 16 + l15;
      bf16x8 a0 = ld_bf8(&wl[o0 * 64 + (((ks * 4 + g) ^ (o0 & 7)) << 3)]);
      bf16x8 a1 = ld_bf8(&wl[o1 * 64 + (((ks * 4 + g) ^ (o1 & 7)) << 3)]);
      #pragma unroll
      for (int cf = 0; cf < 8; ++cf) {
        const u16* bp = xt + (size_t)(b * NN + n0 + cf * 16 + l15) * CC + kt * 64 + ks * 32 + g * 8;
        bf16x8 bb = ld_bf8(bp);
        acc[0][cf] = mfma16(a0, bb, acc[0][cf]);
        acc[1][cf] = mfma16(a1, bb, acc[1][cf]);
      }
    }
    __syncthreads();
  }
  #pragma unroll
  for (int rf = 0; rf < 2; ++rf) {
    #pragma unroll
    for (int r = 0; r < 4; ++r) {
      int c = co0 + w * 32 + rf * 16 + g * 4 + r;
      float bias = bv[c];
      #pragma unroll
      for (int cf = 0; cf < 8; ++cf) {
        int n = n0 + cf * 16 + l15;
        Vt[(size_t)(b * CC + c) * NN + n] = f2bf(acc[rf][cf][r] + bias);
      }
    }
  }
}

// ------------- Kernel 4: flash attention + residual -------------
// Block 512 thr (8 waves), BM=64 q rows, KVBLK=64.
// S-compute: wave w does frags (rf in {2*(w>>2), +1}, cf = w&3).
// Softmax: row = w*8 + (l&7), col-group g8 = l>>3, shfl_xor reduce.
// PV: wave w owns V channels [w*64, w*64+64).
__global__ __launch_bounds__(512) void k_attn(
    const u16* __restrict__ Q, const u16* __restrict__ K, const u16* __restrict__ Vt,
    const float* __restrict__ x, const float* __restrict__ gamma,
    float* __restrict__ out) {
  __shared__ float s_lds[64 * 65];
  __shared__ __align__(16) u16 p_lds[64 * 64];
  __shared__ float alpha_lds[64];
  __shared__ float lsum_lds[64];
  const int b = blockIdx.y;
  const int q0 = blockIdx.x * 64;
  const int t = threadIdx.x;
  const int w = t >> 6, l = t & 63, g = l >> 4, l15 = l & 15;
  const int rfp = w >> 2, cfs = w & 3;
  const int smrow = w * 8 + (l & 7);
  const int g8 = l >> 3;

  bf16x8 qf[2][2];
  #pragma unroll
  for (int i = 0; i < 2; ++i)
    #pragma unroll
    for (int ks = 0; ks < 2; ++ks)
      qf[i][ks] = ld_bf8(Q + (size_t)(b * NN + q0 + (rfp * 2 + i) * 16 + l15) * DQd + ks * 32 + g * 8);

  float m_run = -1e30f, l_run = 0.f;
  f32x4 acc[4][4];
  #pragma unroll
  for (int i = 0; i < 4; ++i)
    #pragma unroll
    for (int j = 0; j < 4; ++j) acc[i][j] = f32x4{0.f, 0.f, 0.f, 0.f};

  for (int kvt = 0; kvt < 64; ++kvt) {
    const int kv0 = kvt * 64;
    // ---- S tile ----
    bf16x8 kf[2];
    #pragma unroll
    for (int ks = 0; ks < 2; ++ks)
      kf[ks] = ld_bf8(K + (size_t)(b * NN + kv0 + cfs * 16 + l15) * DQd + ks * 32 + g * 8);
    #pragma unroll
    for (int i = 0; i < 2; ++i) {
      f32x4 s = f32x4{0.f, 0.f, 0.f, 0.f};
      s = mfma16(qf[i][0], kf[0], s);
      s = mfma16(qf[i][1], kf[1], s);
      int rowb = (rfp * 2 + i) * 16 + g * 4;
      #pragma unroll
      for (int r = 0; r < 4; ++r)
        s_lds[(rowb + r) * 65 + cfs * 16 + l15] = s[r];
    }
    __syncthreads();
    // ---- online softmax ----
    float sv[8]; float mx = -1e30f;
    #pragma unroll
    for (int e = 0; e < 8; ++e) { sv[e] = s_lds[smrow * 65 + g8 * 8 + e]; mx = fmaxf(mx, sv[e]); }
    mx = fmaxf(mx, __shfl_xor(mx, 8));
    mx = fmaxf(mx, __shfl_xor(mx, 16));
    mx = fmaxf(mx, __shfl_xor(mx, 32));
    float m_new = fmaxf(m_run, mx);
    float al = __expf(m_run - m_new);
    float ps = 0.f;
    u32 pw[4];
    #pragma unroll
    for (int e2 = 0; e2 < 4; ++e2) {
      float p0 = __expf(sv[2 * e2] - m_new);
      float p1 = __expf(sv[2 * e2 + 1] - m_new);
      ps += p0 + p1;
      pw[e2] = (u32)f2bf(p0) | ((u32)f2bf(p1) << 16);
    }
    ps += __shfl_xor(ps, 8);
    ps += __shfl_xor(ps, 16);
    ps += __shfl_xor(ps, 32);
    l_run = l_run * al + ps;
    m_run = m_new;
    uint4 pv4 = make_uint4(pw[0], pw[1], pw[2], pw[3]);
    *reinterpret_cast<uint4*>(&p_lds[smrow * 64 + ((g8 ^ (smrow & 7)) << 3)]) = pv4;
    if (g8 == 0) alpha_lds[smrow] = al;
    __syncthreads();
    // ---- rescale + PV ----
    #pragma unroll
    for (int rf = 0; rf < 4; ++rf) {
      #pragma unroll
      for (int r = 0; r < 4; ++r) {
        float a_ = alpha_lds[rf * 16 + g * 4 + r];
        #pragma unroll
        for (int cf = 0; cf < 4; ++cf) acc[rf][cf][r] *= a_;
      }
    }
    #pragma unroll
    for (int ks = 0; ks < 2; ++ks) {
      bf16x8 pf[4];
      #pragma unroll
      for (int rf = 0; rf < 4; ++rf) {
        int row = rf * 16 + l15;
        pf[rf] = ld_bf8(&p_lds[row * 64 + (((ks * 4 + g) ^ (row & 7)) << 3)]);
      }
      #pragma unroll
      for (int cf = 0; cf < 4; ++cf) {
        bf16x8 vf = ld_bf8(Vt + (size_t)(b * CC + w * 64 + cf * 16 + l15) * NN + kv0 + ks * 32 + g * 8);
        #pragma unroll
        for (int rf = 0; rf < 4; ++rf) acc[rf][cf] = mfma16(pf[rf], vf, acc[rf][cf]);
      }
    }
    __syncthreads();
  }
  if (g8 == 0) lsum_lds[smrow] = l_run;
  __syncthreads();
  const float gm = gamma[0];
  #pragma unroll
  for (int rf = 0; rf < 4; ++rf) {
    #pragma unroll
    for (int r = 0; r < 4; ++r) {
      float inv_l = 1.f / lsum_lds[rf * 16 + g * 4 + r];
      int n = q0 + rf * 16 + g * 4 + r;
      #pragma unroll
      for (int cf = 0; cf < 4; ++cf) {
        int c = w * 64 + cf * 16 + l15;
        size_t idx = (size_t)(b * CC + c) * NN + n;
        out[idx] = gm * (acc[rf][cf][r] * inv_l) + x[idx];
      }
    }
  }
}

extern "C" void kernel_launch(void* const* d_in, const int* in_sizes, int n_in,
                              void* d_out, int out_size, void* d_ws, size_t ws_size,
                              hipStream_t stream) {
  (void)in_sizes; (void)n_in; (void)out_size; (void)ws_size;
  const float* x  = (const float*)d_in[0];
  const float* Wq = (const float*)d_in[1];
  const float* bq = (const float*)d_in[2];
  const float* Wk = (const float*)d_in[3];
  const float* bk = (const float*)d_in[4];
  const float* Wv = (const float*)d_in[5];
  const float* bv = (const float*)d_in[6];
  const float* gm = (const float*)d_in[7];
  float* out = (float*)d_out;

  char* ws = (char*)d_ws;
  u16* Xt = (u16*)ws;                                   // 16 MB
  u16* Qw = (u16*)(ws + (size_t)16 * 1024 * 1024);      //  2 MB
  u16* Kw = (u16*)(ws + (size_t)18 * 1024 * 1024);      //  2 MB
  u16* Vt = (u16*)(ws + (size_t)20 * 1024 * 1024);      // 16 MB

  k_transpose<<<dim3(NN / 32, CC / 32, BB), 256, 0, stream>>>(x, Xt);
  k_proj_qk<<<dim3(NN / 64, BB), 512, 0, stream>>>(Xt, Wq, bq, Wk, bk, Qw, Kw);
  k_proj_v<<<dim3(NN / 128, CC / 128, BB), 256, 0, stream>>>(Xt, Wv, bv, Vt);
  k_attn<<<dim3(NN / 64, BB), 512, 0, stream>>>(Qw, Kw, Vt, x, gm, out);
}

// Round 3
// 293.859 us; speedup vs baseline: 1.2239x; 1.2239x over previous
//
#include <hip/hip_runtime.h>
#include <stdint.h>

#define BB 4
#define CC 512
#define NN 4096
#define DQd 64

typedef unsigned short u16;
typedef unsigned int u32;
typedef __bf16 bf16x8 __attribute__((ext_vector_type(8)));
typedef float f32x4 __attribute__((ext_vector_type(4)));

__device__ __forceinline__ u16 f2bf(float f) {
  union { float f; u32 u; } v; v.f = f;
  u32 r = v.u + 0x7FFFu + ((v.u >> 16) & 1u);
  return (u16)(r >> 16);
}

__device__ __forceinline__ bf16x8 ld_bf8(const u16* p) {
  return *reinterpret_cast<const bf16x8*>(p);
}

__device__ __forceinline__ f32x4 mfma16(bf16x8 a, bf16x8 b, f32x4 c) {
  return __builtin_amdgcn_mfma_f32_16x16x32_bf16(a, b, c, 0, 0, 0);
}

// ---------------- Kernel 1: x [B][C][N] f32 -> Xt [B][N][C] bf16 ----------------
__global__ __launch_bounds__(256) void k_transpose(const float* __restrict__ x,
                                                   u16* __restrict__ xt) {
  __shared__ float tile[32][33];
  const int b = blockIdx.z;
  const int n0 = blockIdx.x * 32;
  const int c0 = blockIdx.y * 32;
  const int tj = threadIdx.x & 31;
  const int ti = threadIdx.x >> 5;
  const float* xb = x + (size_t)b * CC * NN;
  #pragma unroll
  for (int i = ti; i < 32; i += 8)
    tile[i][tj] = xb[(size_t)(c0 + i) * NN + (n0 + tj)];
  __syncthreads();
  u16* xtb = xt + (size_t)b * NN * CC;
  #pragma unroll
  for (int i = ti; i < 32; i += 8)
    xtb[(size_t)(n0 + i) * CC + (c0 + tj)] = f2bf(tile[tj][i]);
}

// ------------- Kernel 2: Q,K projection -> Q,K [B][N][64] bf16 -------------
__global__ __launch_bounds__(512) void k_proj_qk(
    const u16* __restrict__ xt, const float* __restrict__ Wq, const float* __restrict__ bq,
    const float* __restrict__ Wk, const float* __restrict__ bk,
    u16* __restrict__ Qo, u16* __restrict__ Ko) {
  __shared__ __align__(16) u16 wl[128 * 64];
  const int b = blockIdx.y;
  const int n0 = blockIdx.x * 64;
  const int t = threadIdx.x;
  const int w = t >> 6, l = t & 63, g = l >> 4, l15 = l & 15;
  const int rw = w & 3, ch = w >> 2;
  f32x4 acc[4];
  #pragma unroll
  for (int i = 0; i < 4; ++i) acc[i] = f32x4{0.f, 0.f, 0.f, 0.f};
  const u16* xrow = xt + (size_t)(b * NN + n0 + rw * 16 + l15) * CC;

  for (int kt = 0; kt < 8; ++kt) {
    #pragma unroll
    for (int i = 0; i < 16; ++i) {
      int e = i * 512 + t;
      int o = e >> 6, cc = e & 63;
      float wv = (o < 64) ? Wq[(size_t)o * CC + kt * 64 + cc]
                          : Wk[(size_t)(o - 64) * CC + kt * 64 + cc];
      wl[o * 64 + ((((cc >> 3) ^ (o & 7)) << 3) | (cc & 7))] = f2bf(wv);
    }
    __syncthreads();
    #pragma unroll
    for (int ks = 0; ks < 2; ++ks) {
      bf16x8 a = ld_bf8(xrow + kt * 64 + ks * 32 + g * 8);
      #pragma unroll
      for (int cf = 0; cf < 4; ++cf) {
        int o = (ch * 4 + cf) * 16 + l15;
        bf16x8 bb = ld_bf8(&wl[o * 64 + (((ks * 4 + g) ^ (o & 7)) << 3)]);
        acc[cf] = mfma16(a, bb, acc[cf]);
      }
    }
    __syncthreads();
  }
  #pragma unroll
  for (int cf = 0; cf < 4; ++cf) {
    int o = (ch * 4 + cf) * 16 + l15;
    float bias = (o < 64) ? bq[o] : bk[o - 64];
    #pragma unroll
    for (int r = 0; r < 4; ++r) {
      int n = n0 + rw * 16 + g * 4 + r;
      u16 val = f2bf(acc[cf][r] + bias);
      if (o < 64) Qo[(size_t)(b * NN + n) * DQd + o] = val;
      else        Ko[(size_t)(b * NN + n) * DQd + (o - 64)] = val;
    }
  }
}

// ------------- Kernel 3: V projection -> Vt [B][512][N] bf16 (transposed) -------------
__global__ __launch_bounds__(256) void k_proj_v(
    const u16* __restrict__ xt, const float* __restrict__ Wv, const float* __restrict__ bv,
    u16* __restrict__ Vt) {
  __shared__ __align__(16) u16 wl[128 * 64];
  const int b = blockIdx.z;
  const int co0 = blockIdx.y * 128;
  const int n0 = blockIdx.x * 128;
  const int t = threadIdx.x;
  const int w = t >> 6, l = t & 63, g = l >> 4, l15 = l & 15;
  f32x4 acc[2][8];
  #pragma unroll
  for (int i = 0; i < 2; ++i)
    #pragma unroll
    for (int j = 0; j < 8; ++j) acc[i][j] = f32x4{0.f, 0.f, 0.f, 0.f};

  for (int kt = 0; kt < 8; ++kt) {
    #pragma unroll
    for (int i = 0; i < 32; ++i) {
      int e = i * 256 + t;
      int o = e >> 6, cc = e & 63;
      float wv = Wv[(size_t)(co0 + o) * CC + kt * 64 + cc];
      wl[o * 64 + ((((cc >> 3) ^ (o & 7)) << 3) | (cc & 7))] = f2bf(wv);
    }
    __syncthreads();
    #pragma unroll
    for (int ks = 0; ks < 2; ++ks) {
      int o0 = w * 32 + l15, o1 = w * 32 + 16 + l15;
      bf16x8 a0 = ld_bf8(&wl[o0 * 64 + (((ks * 4 + g) ^ (o0 & 7)) << 3)]);
      bf16x8 a1 = ld_bf8(&wl[o1 * 64 + (((ks * 4 + g) ^ (o1 & 7)) << 3)]);
      #pragma unroll
      for (int cf = 0; cf < 8; ++cf) {
        const u16* bp = xt + (size_t)(b * NN + n0 + cf * 16 + l15) * CC + kt * 64 + ks * 32 + g * 8;
        bf16x8 bb = ld_bf8(bp);
        acc[0][cf] = mfma16(a0, bb, acc[0][cf]);
        acc[1][cf] = mfma16(a1, bb, acc[1][cf]);
      }
    }
    __syncthreads();
  }
  #pragma unroll
  for (int rf = 0; rf < 2; ++rf) {
    #pragma unroll
    for (int r = 0; r < 4; ++r) {
      int c = co0 + w * 32 + rf * 16 + g * 4 + r;
      float bias = bv[c];
      #pragma unroll
      for (int cf = 0; cf < 8; ++cf) {
        int n = n0 + cf * 16 + l15;
        Vt[(size_t)(b * CC + c) * NN + n] = f2bf(acc[rf][cf][r] + bias);
      }
    }
  }
}

// ------------- Kernel 4: flash attention + residual -------------
// Block 512 thr (8 waves), BM=64 q rows, KVBLK=64.
// Register double-buffered K/V prefetch (issue at top of iter t for t+1).
// 2 barriers/iter: [S-write] bar [softmax, p/alpha write] bar [rescale+PV].
// Safety: s_lds(t+1) writes occur after bar2(t) (all softmax reads done);
// p_lds(t+1) writes occur after bar1(t+1) (all PV(t) reads done).
__global__ __launch_bounds__(512, 2) void k_attn(
    const u16* __restrict__ Q, const u16* __restrict__ K, const u16* __restrict__ Vt,
    const float* __restrict__ x, const float* __restrict__ gamma,
    float* __restrict__ out) {
  __shared__ float s_lds[64 * 65];
  __shared__ __align__(16) u16 p_lds[64 * 64];
  __shared__ float alpha_lds[64];
  __shared__ float lsum_lds[64];
  const int b = blockIdx.y;
  const int q0 = blockIdx.x * 64;
  const int t = threadIdx.x;
  const int w = t >> 6, l = t & 63, g = l >> 4, l15 = l & 15;
  const int rfp = w >> 2, cfs = w & 3;
  const int smrow = w * 8 + (l & 7);
  const int g8 = l >> 3;

  bf16x8 qf[2][2];
  #pragma unroll
  for (int i = 0; i < 2; ++i)
    #pragma unroll
    for (int ks = 0; ks < 2; ++ks)
      qf[i][ks] = ld_bf8(Q + (size_t)(b * NN + q0 + (rfp * 2 + i) * 16 + l15) * DQd + ks * 32 + g * 8);

  const u16* Kp = K + (size_t)(b * NN + cfs * 16 + l15) * DQd + g * 8;
  const u16* Vp = Vt + (size_t)(b * CC + w * 64 + l15) * NN + g * 8;

  // preload tile 0 into current regs
  bf16x8 kc[2], vc[8];
  #pragma unroll
  for (int ks = 0; ks < 2; ++ks) kc[ks] = ld_bf8(Kp + ks * 32);
  #pragma unroll
  for (int cf = 0; cf < 4; ++cf)
    #pragma unroll
    for (int ks = 0; ks < 2; ++ks)
      vc[cf * 2 + ks] = ld_bf8(Vp + (size_t)(cf * 16) * NN + ks * 32);

  float m_run = -1e30f, l_run = 0.f;
  f32x4 acc[4][4];
  #pragma unroll
  for (int i = 0; i < 4; ++i)
    #pragma unroll
    for (int j = 0; j < 4; ++j) acc[i][j] = f32x4{0.f, 0.f, 0.f, 0.f};

  #pragma unroll 2
  for (int kvt = 0; kvt < 64; ++kvt) {
    const int kv0 = kvt * 64;
    const int kvn = (kvt < 63) ? kv0 + 64 : kv0;
    // ---- S tile from resident kc ----
    f32x4 s0 = f32x4{0.f, 0.f, 0.f, 0.f};
    f32x4 s1 = f32x4{0.f, 0.f, 0.f, 0.f};
    s0 = mfma16(qf[0][0], kc[0], s0);
    s0 = mfma16(qf[0][1], kc[1], s0);
    s1 = mfma16(qf[1][0], kc[0], s1);
    s1 = mfma16(qf[1][1], kc[1], s1);
    // ---- issue prefetch of tile t+1 (covered by softmax+PV) ----
    bf16x8 kn[2], vn[8];
    #pragma unroll
    for (int ks = 0; ks < 2; ++ks) kn[ks] = ld_bf8(Kp + (size_t)kvn * DQd + ks * 32);
    #pragma unroll
    for (int cf = 0; cf < 4; ++cf)
      #pragma unroll
      for (int ks = 0; ks < 2; ++ks)
        vn[cf * 2 + ks] = ld_bf8(Vp + (size_t)(cf * 16) * NN + kvn + ks * 32);
    // ---- store S ----
    {
      int rowb0 = (rfp * 2) * 16 + g * 4;
      int rowb1 = (rfp * 2 + 1) * 16 + g * 4;
      #pragma unroll
      for (int r = 0; r < 4; ++r) s_lds[(rowb0 + r) * 65 + cfs * 16 + l15] = s0[r];
      #pragma unroll
      for (int r = 0; r < 4; ++r) s_lds[(rowb1 + r) * 65 + cfs * 16 + l15] = s1[r];
    }
    __syncthreads();
    // ---- online softmax ----
    float sv[8]; float mx = -1e30f;
    #pragma unroll
    for (int e = 0; e < 8; ++e) { sv[e] = s_lds[smrow * 65 + g8 * 8 + e]; mx = fmaxf(mx, sv[e]); }
    mx = fmaxf(mx, __shfl_xor(mx, 8));
    mx = fmaxf(mx, __shfl_xor(mx, 16));
    mx = fmaxf(mx, __shfl_xor(mx, 32));
    float m_new = fmaxf(m_run, mx);
    float al = __expf(m_run - m_new);
    float ps = 0.f;
    u32 pw[4];
    #pragma unroll
    for (int e2 = 0; e2 < 4; ++e2) {
      float p0 = __expf(sv[2 * e2] - m_new);
      float p1 = __expf(sv[2 * e2 + 1] - m_new);
      ps += p0 + p1;
      pw[e2] = (u32)f2bf(p0) | ((u32)f2bf(p1) << 16);
    }
    ps += __shfl_xor(ps, 8);
    ps += __shfl_xor(ps, 16);
    ps += __shfl_xor(ps, 32);
    l_run = l_run * al + ps;
    m_run = m_new;
    uint4 pv4 = make_uint4(pw[0], pw[1], pw[2], pw[3]);
    *reinterpret_cast<uint4*>(&p_lds[smrow * 64 + ((g8 ^ (smrow & 7)) << 3)]) = pv4;
    if (g8 == 0) alpha_lds[smrow] = al;
    __syncthreads();
    // ---- rescale + PV (from resident vc) ----
    #pragma unroll
    for (int rf = 0; rf < 4; ++rf) {
      #pragma unroll
      for (int r = 0; r < 4; ++r) {
        float a_ = alpha_lds[rf * 16 + g * 4 + r];
        #pragma unroll
        for (int cf = 0; cf < 4; ++cf) acc[rf][cf][r] *= a_;
      }
    }
    #pragma unroll
    for (int ks = 0; ks < 2; ++ks) {
      bf16x8 pf[4];
      #pragma unroll
      for (int rf = 0; rf < 4; ++rf) {
        int row = rf * 16 + l15;
        pf[rf] = ld_bf8(&p_lds[row * 64 + (((ks * 4 + g) ^ (row & 7)) << 3)]);
      }
      #pragma unroll
      for (int cf = 0; cf < 4; ++cf) {
        #pragma unroll
        for (int rf = 0; rf < 4; ++rf) acc[rf][cf] = mfma16(pf[rf], vc[cf * 2 + ks], acc[rf][cf]);
      }
    }
    // (no barrier here — see safety note above)
    kc[0] = kn[0]; kc[1] = kn[1];
    #pragma unroll
    for (int i = 0; i < 8; ++i) vc[i] = vn[i];
  }
  if (g8 == 0) lsum_lds[smrow] = l_run;
  __syncthreads();
  const float gm = gamma[0];
  #pragma unroll
  for (int rf = 0; rf < 4; ++rf) {
    #pragma unroll
    for (int r = 0; r < 4; ++r) {
      float inv_l = 1.f / lsum_lds[rf * 16 + g * 4 + r];
      int n = q0 + rf * 16 + g * 4 + r;
      #pragma unroll
      for (int cf = 0; cf < 4; ++cf) {
        int c = w * 64 + cf * 16 + l15;
        size_t idx = (size_t)(b * CC + c) * NN + n;
        out[idx] = gm * (acc[rf][cf][r] * inv_l) + x[idx];
      }
    }
  }
}

extern "C" void kernel_launch(void* const* d_in, const int* in_sizes, int n_in,
                              void* d_out, int out_size, void* d_ws, size_t ws_size,
                              hipStream_t stream) {
  (void)in_sizes; (void)n_in; (void)out_size; (void)ws_size;
  const float* x  = (const float*)d_in[0];
  const float* Wq = (const float*)d_in[1];
  const float* bq = (const float*)d_in[2];
  const float* Wk = (const float*)d_in[3];
  const float* bk = (const float*)d_in[4];
  const float* Wv = (const float*)d_in[5];
  const float* bv = (const float*)d_in[6];
  const float* gm = (const float*)d_in[7];
  float* out = (float*)d_out;

  char* ws = (char*)d_ws;
  u16* Xt = (u16*)ws;                                   // 16 MB
  u16* Qw = (u16*)(ws + (size_t)16 * 1024 * 1024);      //  2 MB
  u16* Kw = (u16*)(ws + (size_t)18 * 1024 * 1024);      //  2 MB
  u16* Vt = (u16*)(ws + (size_t)20 * 1024 * 1024);      // 16 MB

  k_transpose<<<dim3(NN / 32, CC / 32, BB), 256, 0, stream>>>(x, Xt);
  k_proj_qk<<<dim3(NN / 64, BB), 512, 0, stream>>>(Xt, Wq, bq, Wk, bk, Qw, Kw);
  k_proj_v<<<dim3(NN / 128, CC / 128, BB), 256, 0, stream>>>(Xt, Wv, bv, Vt);
  k_attn<<<dim3(NN / 64, BB), 512, 0, stream>>>(Qw, Kw, Vt, x, gm, out);
}